// Round 5
// baseline (220.696 us; speedup 1.0000x reference)
//
#include <hip/hip_runtime.h>
#include <stdint.h>

#define NUM_HEADS 12
#define DH 64
#define SEQ 2048
#define BATCH 2
#define DM 768
#define NQK 1536  // Q cols [0,768) | K cols [768,1536)
#define LOG2E 1.44269504088896340736f

typedef short short8 __attribute__((ext_vector_type(8)));
typedef short short4_t __attribute__((ext_vector_type(4)));
typedef float f32x4 __attribute__((ext_vector_type(4)));

__device__ __forceinline__ short bf16_rne(float f) {
    union { float f; uint32_t u; } v; v.f = f;
    return (short)((v.u + 0x7FFFu + ((v.u >> 16) & 1u)) >> 16);
}

// ---------------- Kernel 0a: W transpose + bf16 convert ----------------
__global__ __launch_bounds__(256) void wt_kernel(const float* __restrict__ Wq,
                                                 const float* __restrict__ Wk,
                                                 short* __restrict__ Wt) {
    __shared__ float tile[32][33];
    int n0 = blockIdx.x * 32;
    int k0 = blockIdx.y * 32;
    int tx = threadIdx.x & 31;
    int ty = threadIdx.x >> 5;
    const float* src = (n0 < DM) ? Wq : Wk;
    int nn0 = (n0 < DM) ? n0 : n0 - DM;
#pragma unroll
    for (int j = 0; j < 4; ++j) {
        int k = ty + 8 * j;
        tile[k][tx] = src[(size_t)(k0 + k) * DM + nn0 + tx];
    }
    __syncthreads();
#pragma unroll
    for (int j = 0; j < 4; ++j) {
        int n = ty + 8 * j;
        Wt[(size_t)(n0 + n) * DM + k0 + tx] = bf16_rne(tile[tx][n]);
    }
}

// ---------------- Kernel 0b: x -> bf16 ----------------
__global__ __launch_bounds__(256) void xb_kernel(const float* __restrict__ x,
                                                 short* __restrict__ Xb) {
    int i = (blockIdx.x * 256 + threadIdx.x) * 4;
    f32x4 v = *(const f32x4*)(x + i);
    short4_t s;
#pragma unroll
    for (int j = 0; j < 4; ++j) s[j] = bf16_rne(v[j]);
    *(short4_t*)(Xb + i) = s;
}

// ---------------- Kernel 0c: mask -> bitmask ----------------
__global__ __launch_bounds__(256) void mpack_kernel(const int* __restrict__ mask,
                                                    unsigned long long* __restrict__ Mb) {
    int wid = (blockIdx.x * 256 + threadIdx.x) >> 6;
    int lane = threadIdx.x & 63;
    size_t base = (size_t)wid * 8;
#pragma unroll
    for (int i = 0; i < 8; ++i) {
        size_t w = base + i;
        int v = mask[w * 64 + lane];
        unsigned long long bal = __ballot(v != 0);
        if (lane == 0) Mb[w] = bal;
    }
}

// ---------------- Kernel 1: projection GEMM (R3 version: 128x128, 2 barriers) ----------------
__global__ __launch_bounds__(256) void proj_kernel(const short* __restrict__ Xb,
                                                   const short* __restrict__ Wt,
                                                   const float* __restrict__ bq,
                                                   const float* __restrict__ bk,
                                                   short* __restrict__ QK) {
    __shared__ short As[128 * 40];
    __shared__ short Bs[128 * 40];
    const int m0 = blockIdx.x * 128;
    const int n0 = blockIdx.y * 128;
    const int t = threadIdx.x;
    const int lane = t & 63;
    const int w = t >> 6;
    const int wr = w >> 1, wc = w & 1;
    const int lr = lane & 15;
    const int lk = lane >> 4;

    f32x4 acc[4][4] = {};

    for (int k0 = 0; k0 < DM; k0 += 32) {
#pragma unroll
        for (int j = 0; j < 2; ++j) {
            int idx = t + 256 * j;
            int row = idx >> 2;
            int ch = idx & 3;
            *(short8*)&As[row * 40 + ch * 8] =
                *(const short8*)&Xb[(size_t)(m0 + row) * DM + k0 + ch * 8];
            *(short8*)&Bs[row * 40 + ch * 8] =
                *(const short8*)&Wt[(size_t)(n0 + row) * DM + k0 + ch * 8];
        }
        __syncthreads();
        short8 a[4], bfr[4];
#pragma unroll
        for (int m = 0; m < 4; ++m)
            a[m] = *(short8*)&As[(wr * 64 + m * 16 + lr) * 40 + lk * 8];
#pragma unroll
        for (int n = 0; n < 4; ++n)
            bfr[n] = *(short8*)&Bs[(wc * 64 + n * 16 + lr) * 40 + lk * 8];
#pragma unroll
        for (int m = 0; m < 4; ++m)
#pragma unroll
            for (int n = 0; n < 4; ++n)
                acc[m][n] = __builtin_amdgcn_mfma_f32_16x16x32_bf16(a[m], bfr[n], acc[m][n], 0, 0, 0);
        __syncthreads();
    }

    const int orow = m0 + wr * 64;
    const int ocol = n0 + wc * 64;
#pragma unroll
    for (int m = 0; m < 4; ++m) {
#pragma unroll
        for (int n = 0; n < 4; ++n) {
            int col = ocol + n * 16 + lr;
            float bias = (col < DM) ? bq[col] : bk[col - DM];
            float scale = (col < DM) ? 0.125f * LOG2E : 1.0f;
#pragma unroll
            for (int r = 0; r < 4; ++r) {
                int row = orow + m * 16 + lk * 4 + r;
                QK[(size_t)row * NQK + col] = bf16_rne((acc[m][n][r] + bias) * scale);
            }
        }
    }
}

// ---------------- Kernel 2: scores + softmax (swapped MFMA, 32 q/wave, dbuf) ----------------
// mfma(K, Q): A=K-frag (16 keys x 32 dh), B=Q-frag. Lane's scores: q = wq+qf*16+lr,
// keys = kt + nf*16 + lk*4 + r. Each K-fragment feeds 2 MFMAs (2 Q frags) -> half the
// ds_read_b128 per unit output vs 16 q/wave.
__global__ __launch_bounds__(256) void attn_kernel(const short* __restrict__ QK,
                                                   const unsigned long long* __restrict__ Mb,
                                                   float* __restrict__ out) {
    __shared__ short Ks[2][64 * 72];
    const int qblk = blockIdx.x;   // 0..15 (128 q rows per block)
    const int h = blockIdx.y;
    const int b = blockIdx.z;
    const int t = threadIdx.x;
    const int lane = t & 63;
    const int w = t >> 6;
    const int lr = lane & 15;
    const int lk = lane >> 4;
    const int wq = qblk * 128 + w * 32;  // wave's first q row (covers 32)

    // Q fragments (B-operand), pre-scaled by 0.125*log2e: aq[qf][ks]
    short8 aq[2][2];
#pragma unroll
    for (int qf = 0; qf < 2; ++qf)
#pragma unroll
        for (int ks = 0; ks < 2; ++ks)
            aq[qf][ks] = *(const short8*)&QK[(size_t)(b * SEQ + wq + qf * 16 + lr) * NQK +
                                             h * DH + ks * 32 + lk * 8];

    const size_t mrow[2] = {
        (size_t)b * SEQ * (SEQ / 64) + (size_t)(wq + lr) * 32,
        (size_t)b * SEQ * (SEQ / 64) + (size_t)(wq + 16 + lr) * 32};

    const int srow = t >> 3, sch = t & 7;
    short8 rs0, rs1;

#define ATT_LOAD(KT)                                                                          \
    rs0 = *(const short8*)&QK[(size_t)(b * SEQ + (KT) + srow) * NQK + DM + h * DH + sch * 8]; \
    rs1 = *(const short8*)&QK[(size_t)(b * SEQ + (KT) + srow + 32) * NQK + DM + h * DH + sch * 8];

#define ATT_WRITE(BUF)                                                                        \
    *(short8*)&Ks[BUF][srow * 72 + sch * 8] = rs0;                                            \
    *(short8*)&Ks[BUF][(srow + 32) * 72 + sch * 8] = rs1;

    // ---- pass A: per-lane sum of exp2 ----
    float lsum[2] = {0.f, 0.f};
    ATT_LOAD(0)
    ATT_WRITE(0)
    __syncthreads();
    int cur = 0;
    for (int kt = 0; kt < SEQ; kt += 64) {
        if (kt + 64 < SEQ) { ATT_LOAD(kt + 64) }
        unsigned long long mb0 = Mb[mrow[0] + (kt >> 6)] >> (lk * 4);
        unsigned long long mb1 = Mb[mrow[1] + (kt >> 6)] >> (lk * 4);
#pragma unroll
        for (int nf = 0; nf < 4; ++nf) {
            short8 k0 = *(short8*)&Ks[cur][(nf * 16 + lr) * 72 + lk * 8];
            short8 k1 = *(short8*)&Ks[cur][(nf * 16 + lr) * 72 + 32 + lk * 8];
            f32x4 a0 = {0.f, 0.f, 0.f, 0.f};
            a0 = __builtin_amdgcn_mfma_f32_16x16x32_bf16(k0, aq[0][0], a0, 0, 0, 0);
            a0 = __builtin_amdgcn_mfma_f32_16x16x32_bf16(k1, aq[0][1], a0, 0, 0, 0);
            f32x4 a1 = {0.f, 0.f, 0.f, 0.f};
            a1 = __builtin_amdgcn_mfma_f32_16x16x32_bf16(k0, aq[1][0], a1, 0, 0, 0);
            a1 = __builtin_amdgcn_mfma_f32_16x16x32_bf16(k1, aq[1][1], a1, 0, 0, 0);
#pragma unroll
            for (int r = 0; r < 4; ++r) {
                float e0 = __builtin_amdgcn_exp2f(a0[r]);
                float e1 = __builtin_amdgcn_exp2f(a1[r]);
                lsum[0] += ((mb0 >> (nf * 16 + r)) & 1ull) ? e0 : 0.f;
                lsum[1] += ((mb1 >> (nf * 16 + r)) & 1ull) ? e1 : 0.f;
            }
        }
        if (kt + 64 < SEQ) { ATT_WRITE(cur ^ 1) }
        __syncthreads();
        cur ^= 1;
    }

    // reduce over the 4 lk lanes sharing each q row
    f32x4 li4[2];
#pragma unroll
    for (int qf = 0; qf < 2; ++qf) {
        float l = lsum[qf];
        l += __shfl_xor(l, 16, 64);
        l += __shfl_xor(l, 32, 64);
        float li = -__log2f(l);
        li4[qf] = (f32x4){li, li, li, li};
    }

    // ---- pass B: recompute, normalize via acc-init, dwordx4 stores ----
    const size_t orow[2] = {
        ((size_t)((b * NUM_HEADS + h) * SEQ) + wq + lr) * SEQ,
        ((size_t)((b * NUM_HEADS + h) * SEQ) + wq + 16 + lr) * SEQ};
    ATT_LOAD(0)
    ATT_WRITE(0)
    __syncthreads();
    cur = 0;
    for (int kt = 0; kt < SEQ; kt += 64) {
        if (kt + 64 < SEQ) { ATT_LOAD(kt + 64) }
        unsigned long long mb0 = Mb[mrow[0] + (kt >> 6)] >> (lk * 4);
        unsigned long long mb1 = Mb[mrow[1] + (kt >> 6)] >> (lk * 4);
#pragma unroll
        for (int nf = 0; nf < 4; ++nf) {
            short8 k0 = *(short8*)&Ks[cur][(nf * 16 + lr) * 72 + lk * 8];
            short8 k1 = *(short8*)&Ks[cur][(nf * 16 + lr) * 72 + 32 + lk * 8];
            f32x4 a0 = __builtin_amdgcn_mfma_f32_16x16x32_bf16(k0, aq[0][0], li4[0], 0, 0, 0);
            a0 = __builtin_amdgcn_mfma_f32_16x16x32_bf16(k1, aq[0][1], a0, 0, 0, 0);
            f32x4 a1 = __builtin_amdgcn_mfma_f32_16x16x32_bf16(k0, aq[1][0], li4[1], 0, 0, 0);
            a1 = __builtin_amdgcn_mfma_f32_16x16x32_bf16(k1, aq[1][1], a1, 0, 0, 0);
            f32x4 p0, p1;
#pragma unroll
            for (int r = 0; r < 4; ++r) {
                float e0 = __builtin_amdgcn_exp2f(a0[r]);
                float e1 = __builtin_amdgcn_exp2f(a1[r]);
                p0[r] = ((mb0 >> (nf * 16 + r)) & 1ull) ? e0 : 0.f;
                p1[r] = ((mb1 >> (nf * 16 + r)) & 1ull) ? e1 : 0.f;
            }
            *(f32x4*)&out[orow[0] + kt + nf * 16 + lk * 4] = p0;
            *(f32x4*)&out[orow[1] + kt + nf * 16 + lk * 4] = p1;
        }
        if (kt + 64 < SEQ) { ATT_WRITE(cur ^ 1) }
        __syncthreads();
        cur ^= 1;
    }
#undef ATT_LOAD
#undef ATT_WRITE
}

extern "C" void kernel_launch(void* const* d_in, const int* in_sizes, int n_in,
                              void* d_out, int out_size, void* d_ws, size_t ws_size,
                              hipStream_t stream) {
    (void)in_sizes; (void)n_in; (void)out_size; (void)ws_size;
    const float* x = (const float*)d_in[0];
    const int* mask = (const int*)d_in[1];
    const float* Wq = (const float*)d_in[2];
    const float* bq = (const float*)d_in[3];
    const float* Wk = (const float*)d_in[4];
    const float* bk = (const float*)d_in[5];
    float* out = (float*)d_out;

    short* Wt = (short*)d_ws;                           // 1536*768 bf16
    short* Xb = Wt + (size_t)NQK * DM;                  // 4096*768 bf16
    short* QK = Xb + (size_t)BATCH * SEQ * DM;          // 4096*1536 bf16
    unsigned long long* Mb =
        (unsigned long long*)(QK + (size_t)BATCH * SEQ * NQK);  // 131072 u64

    wt_kernel<<<dim3(NQK / 32, DM / 32), 256, 0, stream>>>(Wq, Wk, Wt);
    xb_kernel<<<dim3((BATCH * SEQ * DM) / (256 * 4)), 256, 0, stream>>>(x, Xb);
    mpack_kernel<<<dim3((BATCH * SEQ * SEQ / 64) / 32), 256, 0, stream>>>(mask, Mb);
    proj_kernel<<<dim3(BATCH * SEQ / 128, NQK / 128), 256, 0, stream>>>(Xb, Wt, bq, bk, QK);
    attn_kernel<<<dim3(SEQ / 128, NUM_HEADS, BATCH), 256, 0, stream>>>(QK, Mb, out);
}

// Round 6
// 171.746 us; speedup vs baseline: 1.2850x; 1.2850x over previous
//
#include <hip/hip_runtime.h>
#include <stdint.h>

#define NUM_HEADS 12
#define DH 64
#define SEQ 2048
#define BATCH 2
#define DM 768
#define NQK 1536  // Q cols [0,768) | K cols [768,1536)
#define LOG2E 1.44269504088896340736f

typedef short short8 __attribute__((ext_vector_type(8)));
typedef short short4_t __attribute__((ext_vector_type(4)));
typedef float f32x4 __attribute__((ext_vector_type(4)));

__device__ __forceinline__ short bf16_rne(float f) {
    union { float f; uint32_t u; } v; v.f = f;
    return (short)((v.u + 0x7FFFu + ((v.u >> 16) & 1u)) >> 16);
}

// ---------------- Kernel 0: fused prep (wt | xb | mpack), branch on blockIdx ----------------
// blocks [0,1152)          : W transpose+bf16 (48 n-tiles x 24 k-tiles)
// blocks [1152,1920)       : x -> bf16 (768 blocks x 4096 elems)
// blocks [1920,6016)       : mask -> bitmask (4096 blocks)
__global__ __launch_bounds__(256) void prep_kernel(const float* __restrict__ Wq,
                                                   const float* __restrict__ Wk,
                                                   const float* __restrict__ x,
                                                   const int* __restrict__ mask,
                                                   short* __restrict__ Wt,
                                                   short* __restrict__ Xb,
                                                   unsigned long long* __restrict__ Mb) {
    __shared__ float tile[32][33];
    const int bid = blockIdx.x;
    const int t = threadIdx.x;
    if (bid < 1152) {
        // ---- wt ----
        int n0 = (bid % 48) * 32;
        int k0 = (bid / 48) * 32;
        int tx = t & 31;
        int ty = t >> 5;
        const float* src = (n0 < DM) ? Wq : Wk;
        int nn0 = (n0 < DM) ? n0 : n0 - DM;
#pragma unroll
        for (int j = 0; j < 4; ++j) {
            int k = ty + 8 * j;
            tile[k][tx] = src[(size_t)(k0 + k) * DM + nn0 + tx];
        }
        __syncthreads();
#pragma unroll
        for (int j = 0; j < 4; ++j) {
            int n = ty + 8 * j;
            Wt[(size_t)(n0 + n) * DM + k0 + tx] = bf16_rne(tile[tx][n]);
        }
    } else if (bid < 1920) {
        // ---- xb ----
        size_t base = (size_t)(bid - 1152) * 4096;
#pragma unroll
        for (int j = 0; j < 4; ++j) {
            size_t i = base + (size_t)(t + j * 256) * 4;
            f32x4 v = *(const f32x4*)(x + i);
            short4_t s;
#pragma unroll
            for (int e = 0; e < 4; ++e) s[e] = bf16_rne(v[e]);
            *(short4_t*)(Xb + i) = s;
        }
    } else {
        // ---- mpack ----
        int wid = (bid - 1920) * 4 + (t >> 6);
        int lane = t & 63;
        size_t base = (size_t)wid * 8;
#pragma unroll
        for (int i = 0; i < 8; ++i) {
            size_t w = base + i;
            int v = mask[w * 64 + lane];
            unsigned long long bal = __ballot(v != 0);
            if (lane == 0) Mb[w] = bal;
        }
    }
}

// ---------------- Kernel 1: projection GEMM (128x128 tile, BK=64, 2 barriers/step) ----------------
__global__ __launch_bounds__(256) void proj_kernel(const short* __restrict__ Xb,
                                                   const short* __restrict__ Wt,
                                                   const float* __restrict__ bq,
                                                   const float* __restrict__ bk,
                                                   short* __restrict__ QK) {
    __shared__ short As[128 * 72];  // 64 k + 8 pad
    __shared__ short Bs[128 * 72];
    const int m0 = blockIdx.x * 128;
    const int n0 = blockIdx.y * 128;
    const int t = threadIdx.x;
    const int lane = t & 63;
    const int w = t >> 6;
    const int wr = w >> 1, wc = w & 1;
    const int lr = lane & 15;
    const int lk = lane >> 4;

    f32x4 acc[4][4] = {};

    for (int k0 = 0; k0 < DM; k0 += 64) {
#pragma unroll
        for (int j = 0; j < 4; ++j) {
            int idx = t + 256 * j;          // 0..1023
            int row = idx >> 3;             // 0..127
            int ch = idx & 7;               // 8 chunks of 8 bf16 = 64 k
            *(short8*)&As[row * 72 + ch * 8] =
                *(const short8*)&Xb[(size_t)(m0 + row) * DM + k0 + ch * 8];
            *(short8*)&Bs[row * 72 + ch * 8] =
                *(const short8*)&Wt[(size_t)(n0 + row) * DM + k0 + ch * 8];
        }
        __syncthreads();
#pragma unroll
        for (int kk = 0; kk < 2; ++kk) {
            short8 a[4], bfr[4];
#pragma unroll
            for (int m = 0; m < 4; ++m)
                a[m] = *(short8*)&As[(wr * 64 + m * 16 + lr) * 72 + kk * 32 + lk * 8];
#pragma unroll
            for (int n = 0; n < 4; ++n)
                bfr[n] = *(short8*)&Bs[(wc * 64 + n * 16 + lr) * 72 + kk * 32 + lk * 8];
#pragma unroll
            for (int m = 0; m < 4; ++m)
#pragma unroll
                for (int n = 0; n < 4; ++n)
                    acc[m][n] = __builtin_amdgcn_mfma_f32_16x16x32_bf16(a[m], bfr[n], acc[m][n], 0, 0, 0);
        }
        __syncthreads();
    }

    const int orow = m0 + wr * 64;
    const int ocol = n0 + wc * 64;
#pragma unroll
    for (int m = 0; m < 4; ++m) {
#pragma unroll
        for (int n = 0; n < 4; ++n) {
            int col = ocol + n * 16 + lr;
            float bias = (col < DM) ? bq[col] : bk[col - DM];
            float scale = (col < DM) ? 0.125f * LOG2E : 1.0f;
#pragma unroll
            for (int r = 0; r < 4; ++r) {
                int row = orow + m * 16 + lk * 4 + r;
                QK[(size_t)row * NQK + col] = bf16_rne((acc[m][n][r] + bias) * scale);
            }
        }
    }
}

// ---------------- Kernel 2: scores + softmax (R3 layout, 2 K-tiles per barrier pair) ----------------
__global__ __launch_bounds__(256) void attn_kernel(const short* __restrict__ QK,
                                                   const unsigned long long* __restrict__ Mb,
                                                   float* __restrict__ out) {
    __shared__ short Ks[2][64 * 72];
    const int qblk = blockIdx.x;   // 0..31 (64 q rows per block)
    const int h = blockIdx.y;
    const int b = blockIdx.z;
    const int t = threadIdx.x;
    const int lane = t & 63;
    const int w = t >> 6;
    const int lr = lane & 15;
    const int lk = lane >> 4;
    const int wq = qblk * 64 + w * 16;

    // Q fragments (pre-scaled by 0.125*log2e in projection)
    short8 aq[2];
#pragma unroll
    for (int ks = 0; ks < 2; ++ks)
        aq[ks] = *(const short8*)&QK[(size_t)(b * SEQ + wq + lr) * NQK + h * DH + ks * 32 + lk * 8];

    float lrow[4] = {0.f, 0.f, 0.f, 0.f};
    const size_t mrow0 = (size_t)b * SEQ * (SEQ / 64);
    const int srow = t >> 3, sch = t & 7;  // staging coords: 32 rows x 8 chunks per 256 threads

#define ATT_STAGE(KT)                                                                             \
    {                                                                                             \
        _Pragma("unroll") for (int tb = 0; tb < 2; ++tb) {                                        \
            *(short8*)&Ks[tb][srow * 72 + sch * 8] =                                              \
                *(const short8*)&QK[(size_t)(b * SEQ + (KT) + tb * 64 + srow) * NQK + DM +        \
                                    h * DH + sch * 8];                                            \
            *(short8*)&Ks[tb][(srow + 32) * 72 + sch * 8] =                                       \
                *(const short8*)&QK[(size_t)(b * SEQ + (KT) + tb * 64 + srow + 32) * NQK + DM +   \
                                    h * DH + sch * 8];                                            \
        }                                                                                         \
    }

    // ---- pass A: sum of exp2 ----
    for (int kt = 0; kt < SEQ; kt += 128) {
        ATT_STAGE(kt)
        __syncthreads();
#pragma unroll
        for (int tb = 0; tb < 2; ++tb) {
            f32x4 sc[4];
#pragma unroll
            for (int nf = 0; nf < 4; ++nf) {
                short8 k0 = *(short8*)&Ks[tb][(nf * 16 + lr) * 72 + lk * 8];
                short8 k1 = *(short8*)&Ks[tb][(nf * 16 + lr) * 72 + 32 + lk * 8];
                f32x4 a = {0.f, 0.f, 0.f, 0.f};
                a = __builtin_amdgcn_mfma_f32_16x16x32_bf16(aq[0], k0, a, 0, 0, 0);
                a = __builtin_amdgcn_mfma_f32_16x16x32_bf16(aq[1], k1, a, 0, 0, 0);
                sc[nf] = a;
            }
#pragma unroll
            for (int r = 0; r < 4; ++r) {
                int q = wq + lk * 4 + r;
                unsigned long long mbs = Mb[mrow0 + (size_t)q * 32 + ((kt >> 6) + tb)] >> lr;
                float s = 0.f;
#pragma unroll
                for (int nf = 0; nf < 4; ++nf) {
                    float e = __builtin_amdgcn_exp2f(sc[nf][r]);
                    s += ((mbs >> (nf * 16)) & 1ull) ? e : 0.f;
                }
                lrow[r] += s;
            }
        }
        __syncthreads();
    }

    // ---- sum reduce over the 16 key-lanes ----
    float inv[4];
#pragma unroll
    for (int r = 0; r < 4; ++r) {
        float l = lrow[r];
        l += __shfl_xor(l, 1, 64);
        l += __shfl_xor(l, 2, 64);
        l += __shfl_xor(l, 4, 64);
        l += __shfl_xor(l, 8, 64);
        inv[r] = 1.0f / l;
    }

    // ---- pass B: recompute scores, write probs ----
    for (int kt = 0; kt < SEQ; kt += 128) {
        ATT_STAGE(kt)
        __syncthreads();
#pragma unroll
        for (int tb = 0; tb < 2; ++tb) {
            f32x4 sc[4];
#pragma unroll
            for (int nf = 0; nf < 4; ++nf) {
                short8 k0 = *(short8*)&Ks[tb][(nf * 16 + lr) * 72 + lk * 8];
                short8 k1 = *(short8*)&Ks[tb][(nf * 16 + lr) * 72 + 32 + lk * 8];
                f32x4 a = {0.f, 0.f, 0.f, 0.f};
                a = __builtin_amdgcn_mfma_f32_16x16x32_bf16(aq[0], k0, a, 0, 0, 0);
                a = __builtin_amdgcn_mfma_f32_16x16x32_bf16(aq[1], k1, a, 0, 0, 0);
                sc[nf] = a;
            }
#pragma unroll
            for (int r = 0; r < 4; ++r) {
                int q = wq + lk * 4 + r;
                unsigned long long mbs = Mb[mrow0 + (size_t)q * 32 + ((kt >> 6) + tb)] >> lr;
                float* op = &out[((size_t)((b * NUM_HEADS + h) * SEQ + q)) * SEQ + kt + tb * 64 + lr];
#pragma unroll
                for (int nf = 0; nf < 4; ++nf) {
                    float p = __builtin_amdgcn_exp2f(sc[nf][r]) * inv[r];
                    op[nf * 16] = ((mbs >> (nf * 16)) & 1ull) ? p : 0.f;
                }
            }
        }
        __syncthreads();
    }
#undef ATT_STAGE
}

extern "C" void kernel_launch(void* const* d_in, const int* in_sizes, int n_in,
                              void* d_out, int out_size, void* d_ws, size_t ws_size,
                              hipStream_t stream) {
    (void)in_sizes; (void)n_in; (void)out_size; (void)ws_size;
    const float* x = (const float*)d_in[0];
    const int* mask = (const int*)d_in[1];
    const float* Wq = (const float*)d_in[2];
    const float* bq = (const float*)d_in[3];
    const float* Wk = (const float*)d_in[4];
    const float* bk = (const float*)d_in[5];
    float* out = (float*)d_out;

    short* Wt = (short*)d_ws;                           // 1536*768 bf16
    short* Xb = Wt + (size_t)NQK * DM;                  // 4096*768 bf16
    short* QK = Xb + (size_t)BATCH * SEQ * DM;          // 4096*1536 bf16
    unsigned long long* Mb =
        (unsigned long long*)(QK + (size_t)BATCH * SEQ * NQK);  // 131072 u64

    prep_kernel<<<dim3(6016), 256, 0, stream>>>(Wq, Wk, x, mask, Wt, Xb, Mb);
    proj_kernel<<<dim3(BATCH * SEQ / 128, NQK / 128), 256, 0, stream>>>(Xb, Wt, bq, bk, QK);
    attn_kernel<<<dim3(SEQ / 64, NUM_HEADS, BATCH), 256, 0, stream>>>(QK, Mb, out);
}